// Round 2
// baseline (306.705 us; speedup 1.0000x reference)
//
#include <hip/hip_runtime.h>
#include <math.h>

#define HEADS 12
#define HSZ   64
#define SEQ   512
#define BATCH 16
#define HID   768
#define NOUT  1536      // HEADS*2*HSZ
#define NEGQ  1.25e11f  // 1e12 / 8

typedef _Float16 f16x8 __attribute__((ext_vector_type(8)));
typedef _Float16 f16x4 __attribute__((ext_vector_type(4)));
typedef float    f32x4 __attribute__((ext_vector_type(4)));

__device__ __forceinline__ void async_ld16(const void* g, void* l) {
  __builtin_amdgcn_global_load_lds(
      (__attribute__((address_space(1))) void*)g,
      (__attribute__((address_space(3))) void*)l, 16, 0, 0);
}

// ---------------------------------------------------------------------------
// prep: hidden fp32 -> f16 ; W fp32 (K x N) -> Wt f16 (N x K) ; sincos table
// ---------------------------------------------------------------------------
__global__ __launch_bounds__(256) void prep_k(
    const float* __restrict__ hidden, const float* __restrict__ W,
    _Float16* __restrict__ Xb, _Float16* __restrict__ Wt,
    float2* __restrict__ tab)
{
  __shared__ float t_lds[32][33];
  const int b = blockIdx.x;
  const int t = threadIdx.x;
  if (b < 1152) {                     // W transpose: 24 (K/32) x 48 (N/32) tiles
    const int tk = b % 24, tn = b / 24;
    const int k0 = tk * 32, n0 = tn * 32;
    const int tx = t & 31, ty = t >> 5;
#pragma unroll
    for (int r = 0; r < 4; ++r)
      t_lds[ty + r * 8][tx] = W[(size_t)(k0 + ty + r * 8) * NOUT + n0 + tx];
    __syncthreads();
#pragma unroll
    for (int r = 0; r < 4; ++r)
      Wt[(size_t)(n0 + ty + r * 8) * HID + k0 + tx] = (_Float16)t_lds[tx][ty + r * 8];
  } else if (b < 1152 + 6144) {       // hidden convert: 1572864 float4s
    const int idx = (b - 1152) * 256 + t;
    float4 v = ((const float4*)hidden)[idx];
    f16x4 o;
    o.x = (_Float16)v.x; o.y = (_Float16)v.y;
    o.z = (_Float16)v.z; o.w = (_Float16)v.w;
    ((f16x4*)Xb)[idx] = o;
  } else {                            // sincos table: 512 pos x 32 freqs
    const int e = (b - 7296) * 256 + t;   // < 16384
    const int si = e >> 5, fi = e & 31;
    float inv = powf(10000.f, -(float)fi / 32.f);
    float ang = (float)si * inv;
    float sv, cv;
    sincosf(ang, &sv, &cv);
    tab[e] = make_float2(cv, sv);
  }
}

// ---------------------------------------------------------------------------
// GEMM1: Xb(8192x768) @ Wt^T -> +bias -> RoPE -> qb/kb f16 [b,h,s,64]
// 128x128 tile, BK=32, 4 waves, 4x4 frags of 16x16x32 f16 MFMA
// Operand-swapped MFMA: D[quad*4+r] = n (Wt row), D[lane&15] = m (Xb row)
// -> each lane holds 4 consecutive d: RoPE pairs are intra-lane, f16x4 store.
// ---------------------------------------------------------------------------
__global__ __launch_bounds__(256) void gemm1_k(
    const _Float16* __restrict__ Xb, const _Float16* __restrict__ Wt,
    const float* __restrict__ bias, const float2* __restrict__ tab,
    _Float16* __restrict__ qb, _Float16* __restrict__ kb)
{
  __shared__ __align__(16) _Float16 As[128 * 32];
  __shared__ __align__(16) _Float16 Bs[128 * 32];
  const int tid = threadIdx.x;
  const int lane = tid & 63;
  const int m0 = blockIdx.x * 128;
  const int n0 = blockIdx.y * 128;
  const int wm = ((tid >> 6) & 1) * 64;
  const int wn = (tid >> 7) * 64;

  // staging: chunk s in {tid, tid+256}; row = s>>2, k-chunk = (s&3)*8
  const int s0r = tid >> 2, s0c = (tid & 3) * 8;
  const int s1r = (tid + 256) >> 2;
  const _Float16* ag0 = Xb + (size_t)(m0 + s0r) * HID + s0c;
  const _Float16* ag1 = Xb + (size_t)(m0 + s1r) * HID + s0c;
  const _Float16* bg0 = Wt + (size_t)(n0 + s0r) * HID + s0c;
  const _Float16* bg1 = Wt + (size_t)(n0 + s1r) * HID + s0c;
  _Float16* al0 = &As[tid * 8];
  _Float16* al1 = &As[(tid + 256) * 8];
  _Float16* bl0 = &Bs[tid * 8];
  _Float16* bl1 = &Bs[(tid + 256) * 8];

  const int lrow = lane & 15;
  const int lk = (lane >> 4) * 8;

  f32x4 acc[4][4] = {};

  for (int kt = 0; kt < 24; ++kt) {
    async_ld16(ag0, al0);
    async_ld16(ag1, al1);
    async_ld16(bg0, bl0);
    async_ld16(bg1, bl1);
    ag0 += 32; ag1 += 32; bg0 += 32; bg1 += 32;
    __syncthreads();
    f16x8 af[4], bf[4];
#pragma unroll
    for (int i = 0; i < 4; ++i) {
      af[i] = *(const f16x8*)&As[(wm + i * 16 + lrow) * 32 + lk];
      bf[i] = *(const f16x8*)&Bs[(wn + i * 16 + lrow) * 32 + lk];
    }
#pragma unroll
    for (int i = 0; i < 4; ++i)
#pragma unroll
      for (int j = 0; j < 4; ++j)
        acc[i][j] = __builtin_amdgcn_mfma_f32_16x16x32_f16(bf[j], af[i], acc[i][j], 0, 0, 0);
    __syncthreads();
  }

  // epilogue: bias + interleaved RoPE (pairs intra-lane), f16x4 stores
  const int qlane = lane >> 4;
  const int mlane = m0 + wm + (lane & 15);
#pragma unroll
  for (int j = 0; j < 4; ++j) {
    const int nb = n0 + wn + j * 16 + qlane * 4;   // 4 consecutive n = d dims
    const float4 b4 = *(const float4*)&bias[nb];
    const int d0 = nb & 63;
    const int h = nb >> 7;
    _Float16* dst = ((nb >> 6) & 1) ? kb : qb;
    const int fi0 = d0 >> 1;                        // even
#pragma unroll
    for (int i = 0; i < 4; ++i) {
      const int m = mlane + i * 16;
      const int si = m & (SEQ - 1);
      const int bb = m >> 9;
      const float4 cs = *(const float4*)&tab[si * 32 + fi0];  // c0,s0,c1,s1
      const float v0 = acc[i][j][0] + b4.x;
      const float v1 = acc[i][j][1] + b4.y;
      const float v2 = acc[i][j][2] + b4.z;
      const float v3 = acc[i][j][3] + b4.w;
      f16x4 o;
      o.x = (_Float16)fmaf(v0, cs.x, -v1 * cs.y);
      o.y = (_Float16)fmaf(v1, cs.x, v0 * cs.y);
      o.z = (_Float16)fmaf(v2, cs.z, -v3 * cs.w);
      o.w = (_Float16)fmaf(v3, cs.z, v2 * cs.w);
      *(f16x4*)&dst[((size_t)(bb * HEADS + h) * SEQ + si) * HSZ + d0] = o;
    }
  }
}

// ---------------------------------------------------------------------------
// GEMM2: per (b,h): S = Q K^T (512x512x64), scale + causal/pad mask, fp32 out
// Operand-swapped MFMA -> lane holds 4 consecutive n for one m -> float4 store
// blocks fully below diagonal skip compute (|S/8| << threshold)
// ---------------------------------------------------------------------------
__global__ __launch_bounds__(256) void gemm2_k(
    const _Float16* __restrict__ qb, const _Float16* __restrict__ kb,
    const int* __restrict__ am, float* __restrict__ out)
{
  __shared__ __align__(16) _Float16 Qs[2 * 128 * 32];
  __shared__ __align__(16) _Float16 Ks[2 * 128 * 32];
  const int tid = threadIdx.x;
  const int bh = blockIdx.y;
  const int bb = bh / HEADS;
  const int mt = blockIdx.x >> 2, nt = blockIdx.x & 3;
  const int m0 = mt * 128, n0 = nt * 128;
  const int* amb = am + bb * SEQ;
  float* obase = out + (size_t)bh * SEQ * SEQ;

  if (nt < mt) {  // fully masked by tril(k=-1): write -(tri+pad)*NEG_BIG/8
#pragma unroll
    for (int q = 0; q < 16; ++q) {
      const int f = q * 256 + tid;
      const int row = f >> 5, c4 = (f & 31) * 4;
      const int m = m0 + row;
      const float amm = (float)amb[m];
      const int nb = n0 + c4;
      const int4 a4 = *(const int4*)&amb[nb];
      float4 v;
      v.x = -(2.f - amm * (float)a4.x) * NEGQ;
      v.y = -(2.f - amm * (float)a4.y) * NEGQ;
      v.z = -(2.f - amm * (float)a4.z) * NEGQ;
      v.w = -(2.f - amm * (float)a4.w) * NEGQ;
      *(float4*)&obase[(size_t)m * SEQ + nb] = v;
    }
    return;
  }

  const _Float16* qg = qb + (size_t)bh * SEQ * HSZ;
  const _Float16* kg = kb + (size_t)bh * SEQ * HSZ;
#pragma unroll
  for (int ct = 0; ct < 4; ++ct) {
    const int s = ct * 256 + tid;
    const int half = s >> 9, row = (s >> 2) & 127, c8 = (s & 3) * 8;
    async_ld16(qg + (size_t)(m0 + row) * HSZ + half * 32 + c8, &Qs[s * 8]);
    async_ld16(kg + (size_t)(n0 + row) * HSZ + half * 32 + c8, &Ks[s * 8]);
  }
  __syncthreads();

  const int lane = tid & 63;
  const int wm = ((tid >> 6) & 1) * 64;
  const int wn = (tid >> 7) * 64;
  const int lrow = lane & 15;
  const int lk = (lane >> 4) * 8;
  f32x4 acc[4][4] = {};
#pragma unroll
  for (int half = 0; half < 2; ++half) {
    f16x8 af[4], bf[4];
#pragma unroll
    for (int i = 0; i < 4; ++i) {
      af[i] = *(const f16x8*)&Qs[half * 4096 + (wm + i * 16 + lrow) * 32 + lk];
      bf[i] = *(const f16x8*)&Ks[half * 4096 + (wn + i * 16 + lrow) * 32 + lk];
    }
#pragma unroll
    for (int i = 0; i < 4; ++i)
#pragma unroll
      for (int j = 0; j < 4; ++j)
        acc[i][j] = __builtin_amdgcn_mfma_f32_16x16x32_f16(bf[j], af[i], acc[i][j], 0, 0, 0);
  }

  // epilogue: lane holds 4 consecutive n for one m -> float4 stores
  const int qlane = lane >> 4;
  const int mlane = m0 + wm + (lane & 15);
#pragma unroll
  for (int i = 0; i < 4; ++i) {
    const int m = mlane + i * 16;
    const float amm = (float)amb[m];
    float* orow = obase + (size_t)m * SEQ;
#pragma unroll
    for (int j = 0; j < 4; ++j) {
      const int nb = n0 + wn + j * 16 + qlane * 4;
      const int4 a4 = *(const int4*)&amb[nb];
      float4 v;
      v.x = fmaf(acc[i][j][0], 0.125f,
                 -((float)(nb + 0 < m) + (1.f - amm * (float)a4.x)) * NEGQ);
      v.y = fmaf(acc[i][j][1], 0.125f,
                 -((float)(nb + 1 < m) + (1.f - amm * (float)a4.y)) * NEGQ);
      v.z = fmaf(acc[i][j][2], 0.125f,
                 -((float)(nb + 2 < m) + (1.f - amm * (float)a4.z)) * NEGQ);
      v.w = fmaf(acc[i][j][3], 0.125f,
                 -((float)(nb + 3 < m) + (1.f - amm * (float)a4.w)) * NEGQ);
      *(float4*)&orow[nb] = v;
    }
  }
}

// ---------------------------------------------------------------------------
extern "C" void kernel_launch(void* const* d_in, const int* in_sizes, int n_in,
                              void* d_out, int out_size, void* d_ws, size_t ws_size,
                              hipStream_t stream) {
  const float* hidden = (const float*)d_in[0];
  const int*   am     = (const int*)d_in[1];
  const float* W      = (const float*)d_in[2];
  const float* bias   = (const float*)d_in[3];
  float* out = (float*)d_out;
  char* ws = (char*)d_ws;
  // workspace layout (all 16B-aligned): total 40,239,104 B
  _Float16* Xb = (_Float16*)(ws);               // 8192*768*2   = 12,582,912
  _Float16* Wt = (_Float16*)(ws + 12582912);    // 1536*768*2   =  2,359,296
  _Float16* qb = (_Float16*)(ws + 14942208);    // 16*12*512*64*2 = 12,582,912
  _Float16* kb = (_Float16*)(ws + 27525120);    // 12,582,912
  float2*   tab = (float2*)(ws + 40108032);     // 512*32*8 = 131,072

  prep_k<<<dim3(7360), dim3(256), 0, stream>>>(hidden, W, Xb, Wt, tab);
  gemm1_k<<<dim3(64, 12), dim3(256), 0, stream>>>(Xb, Wt, bias, tab, qb, kb);
  gemm2_k<<<dim3(16, 192), dim3(256), 0, stream>>>(qb, kb, am, out);
}

// Round 3
// 274.814 us; speedup vs baseline: 1.1160x; 1.1160x over previous
//
#include <hip/hip_runtime.h>
#include <math.h>

#define HEADS 12
#define HSZ   64
#define SEQ   512
#define HID   768
#define NOUT  1536      // HEADS*2*HSZ
#define NEGQ  1.25e11f  // 1e12 / 8

typedef _Float16 f16x8 __attribute__((ext_vector_type(8)));
typedef _Float16 f16x4 __attribute__((ext_vector_type(4)));
typedef float    f32x4 __attribute__((ext_vector_type(4)));
typedef int      i32x4 __attribute__((ext_vector_type(4)));
typedef int      i32x8 __attribute__((ext_vector_type(8)));

__device__ __forceinline__ void async_ld16(const void* g, void* l) {
  __builtin_amdgcn_global_load_lds(
      (__attribute__((address_space(1))) void*)g,
      (__attribute__((address_space(3))) void*)l, 16, 0, 0);
}

// ---------------------------------------------------------------------------
// prep: hidden fp32 -> fp8 e4m3 (k-major) ; W fp32 (KxN) -> Wt8 fp8 (NxK) ;
// sincos table
// ---------------------------------------------------------------------------
__global__ __launch_bounds__(256) void prep_k(
    const float* __restrict__ hidden, const float* __restrict__ W,
    unsigned char* __restrict__ Xb8, unsigned char* __restrict__ Wt8,
    float2* __restrict__ tab)
{
  __shared__ float t_lds[32][33];
  const int b = blockIdx.x;
  const int t = threadIdx.x;
  if (b < 1152) {                     // W transpose+cvt: 24 (K/32) x 48 (N/32)
    const int tk = b % 24, tn = b / 24;
    const int k0 = tk * 32, n0 = tn * 32;
    const int tx = t & 31, ty = t >> 5;
#pragma unroll
    for (int r = 0; r < 4; ++r)
      t_lds[ty + r * 8][tx] = W[(size_t)(k0 + ty + r * 8) * NOUT + n0 + tx];
    __syncthreads();
    const int nl = t >> 3, kg = t & 7;     // each thread packs 4 k into 1 int
    int w = __builtin_amdgcn_cvt_pk_fp8_f32(t_lds[kg * 4 + 0][nl],
                                            t_lds[kg * 4 + 1][nl], 0, false);
    w = __builtin_amdgcn_cvt_pk_fp8_f32(t_lds[kg * 4 + 2][nl],
                                        t_lds[kg * 4 + 3][nl], w, true);
    *(int*)&Wt8[(size_t)(n0 + nl) * HID + k0 + kg * 4] = w;
  } else if (b < 1152 + 1536) {       // hidden cvt: 393216 threads x 16 k
    const int idx = (b - 1152) * 256 + t;
    const float4* src = (const float4*)hidden + (size_t)idx * 4;
    float4 v0 = src[0], v1 = src[1], v2 = src[2], v3 = src[3];
    int4 o;
    o.x = __builtin_amdgcn_cvt_pk_fp8_f32(v0.x, v0.y, 0, false);
    o.x = __builtin_amdgcn_cvt_pk_fp8_f32(v0.z, v0.w, o.x, true);
    o.y = __builtin_amdgcn_cvt_pk_fp8_f32(v1.x, v1.y, 0, false);
    o.y = __builtin_amdgcn_cvt_pk_fp8_f32(v1.z, v1.w, o.y, true);
    o.z = __builtin_amdgcn_cvt_pk_fp8_f32(v2.x, v2.y, 0, false);
    o.z = __builtin_amdgcn_cvt_pk_fp8_f32(v2.z, v2.w, o.z, true);
    o.w = __builtin_amdgcn_cvt_pk_fp8_f32(v3.x, v3.y, 0, false);
    o.w = __builtin_amdgcn_cvt_pk_fp8_f32(v3.z, v3.w, o.w, true);
    ((int4*)Xb8)[idx] = o;
  } else {                            // sincos table: 512 pos x 32 freqs
    const int e = (b - 2688) * 256 + t;   // < 16384
    const int si = e >> 5, fi = e & 31;
    float inv = powf(10000.f, -(float)fi / 32.f);
    float ang = (float)si * inv;
    float sv, cv;
    sincosf(ang, &sv, &cv);
    tab[e] = make_float2(cv, sv);
  }
}

// ---------------------------------------------------------------------------
// GEMM1: Xb8(8192x768 fp8) @ Wt8^T -> +bias -> RoPE -> qb/kb f16 [b,h,s,64]
// MX-scaled fp8 MFMA 16x16x128 (scale=1.0), BK=128, 6 K-iters, 128x128 tile.
// LDS 32B-pair XOR swizzle (applied via source permutation at staging) keeps
// frag b128 reads bank-even. Operand-swapped: lane&15=m, quad*4+reg=n.
// ---------------------------------------------------------------------------
__global__ __launch_bounds__(256) void gemm1_k(
    const unsigned char* __restrict__ Xb8, const unsigned char* __restrict__ Wt8,
    const float* __restrict__ bias, const float2* __restrict__ tab,
    _Float16* __restrict__ qb, _Float16* __restrict__ kb)
{
  __shared__ __align__(16) int As4[4096];   // 128 rows x 128 fp8
  __shared__ __align__(16) int Bs4[4096];
  const int tid = threadIdx.x;
  const int lane = tid & 63;
  const int m0 = blockIdx.x * 128;
  const int n0 = blockIdx.y * 128;
  const int wm = ((tid >> 6) & 1) * 64;
  const int wn = (tid >> 7) * 64;
  const int lrow = lane & 15;
  const int q = lane >> 4;

  f32x4 acc[4][4] = {};

  for (int kt = 0; kt < 6; ++kt) {
    const int kbase = kt * 128;
#pragma unroll
    for (int c = 0; c < 4; ++c) {
      const int s = tid + c * 256;
      const int row = s >> 3, cc = s & 7;
      // lds 32B-pair p holds global pair p ^ (row&3)
      const int so = (((cc >> 1) ^ (row & 3)) << 5) + ((cc & 1) << 4);
      async_ld16(Xb8 + (size_t)(m0 + row) * HID + kbase + so, (char*)As4 + s * 16);
      async_ld16(Wt8 + (size_t)(n0 + row) * HID + kbase + so, (char*)Bs4 + s * 16);
    }
    __syncthreads();
    i32x8 af[4], bf[4];
#pragma unroll
    for (int i = 0; i < 4; ++i) {
      const int ra = wm + i * 16 + lrow;
      const int oa = ra * 32 + ((q ^ (ra & 3)) << 3);
      i32x4 lo = *(const i32x4*)&As4[oa];
      i32x4 hi = *(const i32x4*)&As4[oa + 4];
      af[i] = (i32x8){lo.x, lo.y, lo.z, lo.w, hi.x, hi.y, hi.z, hi.w};
      const int rb = wn + i * 16 + lrow;
      const int ob = rb * 32 + ((q ^ (rb & 3)) << 3);
      lo = *(const i32x4*)&Bs4[ob];
      hi = *(const i32x4*)&Bs4[ob + 4];
      bf[i] = (i32x8){lo.x, lo.y, lo.z, lo.w, hi.x, hi.y, hi.z, hi.w};
    }
#pragma unroll
    for (int i = 0; i < 4; ++i)
#pragma unroll
      for (int j = 0; j < 4; ++j)
        acc[i][j] = __builtin_amdgcn_mfma_scale_f32_16x16x128_f8f6f4(
            bf[j], af[i], acc[i][j], 0, 0,
            0, 0x7F7F7F7F, 0, 0x7F7F7F7F);   // E8M0 0x7F = 1.0 in every byte
    __syncthreads();
  }

  // epilogue: bias + interleaved RoPE (pairs intra-lane), f16x4 stores
  const int qlane = lane >> 4;
  const int mlane = m0 + wm + (lane & 15);
#pragma unroll
  for (int j = 0; j < 4; ++j) {
    const int nb = n0 + wn + j * 16 + qlane * 4;   // 4 consecutive n = d dims
    const float4 b4 = *(const float4*)&bias[nb];
    const int d0 = nb & 63;
    const int h = nb >> 7;
    _Float16* dst = ((nb >> 6) & 1) ? kb : qb;
    const int fi0 = d0 >> 1;                        // even
#pragma unroll
    for (int i = 0; i < 4; ++i) {
      const int m = mlane + i * 16;
      const int si = m & (SEQ - 1);
      const int bb = m >> 9;
      const float4 cs = *(const float4*)&tab[si * 32 + fi0];  // c0,s0,c1,s1
      const float v0 = acc[i][j][0] + b4.x;
      const float v1 = acc[i][j][1] + b4.y;
      const float v2 = acc[i][j][2] + b4.z;
      const float v3 = acc[i][j][3] + b4.w;
      f16x4 o;
      o.x = (_Float16)fmaf(v0, cs.x, -v1 * cs.y);
      o.y = (_Float16)fmaf(v1, cs.x, v0 * cs.y);
      o.z = (_Float16)fmaf(v2, cs.z, -v3 * cs.w);
      o.w = (_Float16)fmaf(v3, cs.z, v2 * cs.w);
      *(f16x4*)&dst[((size_t)(bb * HEADS + h) * SEQ + si) * HSZ + d0] = o;
    }
  }
}

// ---------------------------------------------------------------------------
// GEMM2: per (b,h): S = Q K^T (512x512x64), scale + causal/pad mask, fp32 out
// No LDS, no barriers: K=64 lives in 16 register frags loaded from global.
// Nontemporal float4 stores (write-once 201 MB output).
// ---------------------------------------------------------------------------
__global__ __launch_bounds__(256) void gemm2_k(
    const _Float16* __restrict__ qb, const _Float16* __restrict__ kb,
    const int* __restrict__ am, float* __restrict__ out)
{
  const int tid = threadIdx.x;
  const int bh = blockIdx.y;
  const int bb = bh / HEADS;
  const int mt = blockIdx.x >> 2, nt = blockIdx.x & 3;
  const int m0 = mt * 128, n0 = nt * 128;
  const int* amb = am + bb * SEQ;
  float* obase = out + (size_t)bh * SEQ * SEQ;

  if (nt < mt) {  // fully masked by tril(k=-1)
#pragma unroll
    for (int p = 0; p < 16; ++p) {
      const int f = p * 256 + tid;
      const int row = f >> 5, c4 = (f & 31) * 4;
      const int m = m0 + row;
      const float amm = (float)amb[m];
      const int nb = n0 + c4;
      const int4 a4 = *(const int4*)&amb[nb];
      f32x4 v;
      v[0] = -(2.f - amm * (float)a4.x) * NEGQ;
      v[1] = -(2.f - amm * (float)a4.y) * NEGQ;
      v[2] = -(2.f - amm * (float)a4.z) * NEGQ;
      v[3] = -(2.f - amm * (float)a4.w) * NEGQ;
      __builtin_nontemporal_store(v, (f32x4*)&obase[(size_t)m * SEQ + nb]);
    }
    return;
  }

  const _Float16* qg = qb + (size_t)bh * SEQ * HSZ;
  const _Float16* kg = kb + (size_t)bh * SEQ * HSZ;
  const int lane = tid & 63;
  const int wm = ((tid >> 6) & 1) * 64;
  const int wn = (tid >> 7) * 64;
  const int lrow = lane & 15;
  const int lk = (lane >> 4) * 8;

  f16x8 af[4][2], bf[4][2];
#pragma unroll
  for (int i = 0; i < 4; ++i)
#pragma unroll
    for (int h = 0; h < 2; ++h) {
      af[i][h] = *(const f16x8*)(qg + (size_t)(m0 + wm + i * 16 + lrow) * HSZ + h * 32 + lk);
      bf[i][h] = *(const f16x8*)(kg + (size_t)(n0 + wn + i * 16 + lrow) * HSZ + h * 32 + lk);
    }

  f32x4 acc[4][4] = {};
#pragma unroll
  for (int h = 0; h < 2; ++h)
#pragma unroll
    for (int i = 0; i < 4; ++i)
#pragma unroll
      for (int j = 0; j < 4; ++j)
        acc[i][j] = __builtin_amdgcn_mfma_f32_16x16x32_f16(bf[j][h], af[i][h], acc[i][j], 0, 0, 0);

  // epilogue: lane holds 4 consecutive n for one m -> nontemporal float4
  const int qlane = lane >> 4;
  const int mlane = m0 + wm + (lane & 15);
#pragma unroll
  for (int i = 0; i < 4; ++i) {
    const int m = mlane + i * 16;
    const float amm = (float)amb[m];
    float* orow = obase + (size_t)m * SEQ;
#pragma unroll
    for (int j = 0; j < 4; ++j) {
      const int nb = n0 + wn + j * 16 + qlane * 4;
      const int4 a4 = *(const int4*)&amb[nb];
      f32x4 v;
      v[0] = fmaf(acc[i][j][0], 0.125f,
                  -((float)(nb + 0 < m) + (1.f - amm * (float)a4.x)) * NEGQ);
      v[1] = fmaf(acc[i][j][1], 0.125f,
                  -((float)(nb + 1 < m) + (1.f - amm * (float)a4.y)) * NEGQ);
      v[2] = fmaf(acc[i][j][2], 0.125f,
                  -((float)(nb + 2 < m) + (1.f - amm * (float)a4.z)) * NEGQ);
      v[3] = fmaf(acc[i][j][3], 0.125f,
                  -((float)(nb + 3 < m) + (1.f - amm * (float)a4.w)) * NEGQ);
      __builtin_nontemporal_store(v, (f32x4*)&orow[nb]);
    }
  }
}

// ---------------------------------------------------------------------------
extern "C" void kernel_launch(void* const* d_in, const int* in_sizes, int n_in,
                              void* d_out, int out_size, void* d_ws, size_t ws_size,
                              hipStream_t stream) {
  const float* hidden = (const float*)d_in[0];
  const int*   am     = (const int*)d_in[1];
  const float* W      = (const float*)d_in[2];
  const float* bias   = (const float*)d_in[3];
  float* out = (float*)d_out;
  char* ws = (char*)d_ws;
  // workspace layout (16B-aligned), total ~32.8 MB
  unsigned char* Xb8 = (unsigned char*)(ws);              // 8192*768  = 6,291,456
  unsigned char* Wt8 = (unsigned char*)(ws + 6291456);    // 1536*768  = 1,179,648
  _Float16* qb = (_Float16*)(ws + 7471104);               // 12,582,912
  _Float16* kb = (_Float16*)(ws + 20054016);              // 12,582,912
  float2*   tab = (float2*)(ws + 32636928);               // 131,072

  prep_k<<<dim3(2752), dim3(256), 0, stream>>>(hidden, W, Xb8, Wt8, tab);
  gemm1_k<<<dim3(64, 12), dim3(256), 0, stream>>>(Xb8, Wt8, bias, tab, qb, kb);
  gemm2_k<<<dim3(16, 192), dim3(256), 0, stream>>>(qb, kb, am, out);
}